// Round 1
// baseline (1795.594 us; speedup 1.0000x reference)
//
#include <hip/hip_runtime.h>
#include <math.h>

#define HH 12
#define SS 2048
#define DM 768
#define DK 64

// ---------------------------------------------------------------------------
// GEMM: C[M=4096, 768] = A[M,768] @ W[768,768] + bias
// 64x64 tile, 256 threads, 4x4 micro-tile, K-tile 16.
// A staged transposed (Ast[k][m]) so fragment reads are float4 (ds_read_b128).
// SPLIT=true stores into head-split layout [B,H,S,64].
// ---------------------------------------------------------------------------
template <bool SPLIT>
__global__ __launch_bounds__(256) void gemm_bias_kernel(
        const float* __restrict__ A, const float* __restrict__ W,
        const float* __restrict__ bias, float* __restrict__ C)
{
    __shared__ float Ast[16][68];
    __shared__ float Bs[16][68];

    const int tid = threadIdx.x;
    const int tx = tid & 15, ty = tid >> 4;
    const int n0 = blockIdx.x * 64;
    const int m0 = blockIdx.y * 64;

    float acc[4][4] = {};

    for (int kt = 0; kt < 48; ++kt) {
        __syncthreads();
        // stage A tile transposed: Ast[c][r] = A[m0+r][kt*16+c]
        #pragma unroll
        for (int it = 0; it < 4; ++it) {
            int idx = tid + it * 256;
            int r = idx >> 4, c = idx & 15;
            Ast[c][r] = A[(size_t)(m0 + r) * DM + kt * 16 + c];
        }
        // stage B tile natural: Bs[r][c] = W[kt*16+r][n0+c]
        {
            int r = tid >> 4, c = tid & 15;
            *(float4*)&Bs[r][c << 2] =
                *(const float4*)&W[(size_t)(kt * 16 + r) * DM + n0 + (c << 2)];
        }
        __syncthreads();

        #pragma unroll 4
        for (int kk = 0; kk < 16; ++kk) {
            float4 a4 = *(const float4*)&Ast[kk][ty << 2];
            float4 b4 = *(const float4*)&Bs[kk][tx << 2];
            float av[4] = {a4.x, a4.y, a4.z, a4.w};
            float bv[4] = {b4.x, b4.y, b4.z, b4.w};
            #pragma unroll
            for (int i = 0; i < 4; ++i)
                #pragma unroll
                for (int j = 0; j < 4; ++j)
                    acc[i][j] = fmaf(av[i], bv[j], acc[i][j]);
        }
    }

    const float4 bb4 = *(const float4*)&bias[n0 + (tx << 2)];
    const float bvv[4] = {bb4.x, bb4.y, bb4.z, bb4.w};
    #pragma unroll
    for (int i = 0; i < 4; ++i) {
        int m = m0 + ty * 4 + i;
        float4 o;
        o.x = acc[i][0] + bvv[0];
        o.y = acc[i][1] + bvv[1];
        o.z = acc[i][2] + bvv[2];
        o.w = acc[i][3] + bvv[3];
        if (SPLIT) {
            int b_ = m >> 11, s_ = m & 2047;
            int h = blockIdx.x;  // n0/64; N-tile == head since DK==64
            *(float4*)&C[(((size_t)(b_ * HH + h) * SS + s_) << 6) + (tx << 2)] = o;
        } else {
            *(float4*)&C[(size_t)m * DM + n0 + (tx << 2)] = o;
        }
    }
}

// ---------------------------------------------------------------------------
// Fused attention per (b,h) and 64-query tile:
//   pass A: online row max/sum of exp over all 2048 keys (QK^T recompute)
//   pass B: recompute scores, write p = exp(s-m)/l to d_out attn region,
//           accumulate O = P@V in registers, store ctx in [B,S,768] layout.
// ---------------------------------------------------------------------------
__global__ __launch_bounds__(256) void attn_kernel(
        const float* __restrict__ Qh, const float* __restrict__ Kh,
        const float* __restrict__ Vh, float* __restrict__ attnW,
        float* __restrict__ ctx)
{
    __shared__ float Qt[64][68];   // Q tile transposed [d][q]
    __shared__ float KVs[64][68];  // K tile transposed [d][k]  /  V tile [k][d]
    __shared__ float Ps[64][68];   // P tile [q][k]
    __shared__ float redM[64][17];
    __shared__ float redL[64][17];
    __shared__ float Mrow[64];
    __shared__ float Rlrow[64];

    const int tid = threadIdx.x;
    const int tx = tid & 15, ty = tid >> 4;
    const int qt = blockIdx.x;  // 0..31
    const int bh = blockIdx.y;  // 0..23
    const int q0 = qt * 64;
    const size_t base = (size_t)bh * SS * DK;

    // stage Q tile transposed (reused across all 32 key tiles, both passes)
    for (int idx = tid; idx < 4096; idx += 256) {
        int q = idx >> 6, d = idx & 63;
        Qt[d][q] = Qh[base + (size_t)(q0 + q) * DK + d];
    }

    float mloc[4], lloc[4];
    #pragma unroll
    for (int i = 0; i < 4; ++i) { mloc[i] = -INFINITY; lloc[i] = 0.f; }

    // ---------------- pass A: row max & sum ----------------
    for (int kt = 0; kt < 32; ++kt) {
        __syncthreads();
        for (int idx = tid; idx < 4096; idx += 256) {
            int k = idx >> 6, d = idx & 63;
            KVs[d][k] = Kh[base + (size_t)(kt * 64 + k) * DK + d];
        }
        __syncthreads();

        float s[4][4] = {};
        #pragma unroll 8
        for (int d = 0; d < 64; ++d) {
            float4 a4 = *(const float4*)&Qt[d][ty << 2];
            float4 b4 = *(const float4*)&KVs[d][tx << 2];
            float av[4] = {a4.x, a4.y, a4.z, a4.w};
            float bv[4] = {b4.x, b4.y, b4.z, b4.w};
            #pragma unroll
            for (int i = 0; i < 4; ++i)
                #pragma unroll
                for (int j = 0; j < 4; ++j)
                    s[i][j] = fmaf(av[i], bv[j], s[i][j]);
        }
        #pragma unroll
        for (int i = 0; i < 4; ++i)
            #pragma unroll
            for (int j = 0; j < 4; ++j) {
                float v = s[i][j] * 0.125f;
                if (v > mloc[i]) {
                    lloc[i] = lloc[i] * __expf(mloc[i] - v) + 1.f;
                    mloc[i] = v;
                } else {
                    lloc[i] += __expf(v - mloc[i]);
                }
            }
    }

    #pragma unroll
    for (int i = 0; i < 4; ++i) {
        redM[ty * 4 + i][tx] = mloc[i];
        redL[ty * 4 + i][tx] = lloc[i];
    }
    __syncthreads();
    if (tid < 64) {
        float M = -INFINITY;
        for (int t = 0; t < 16; ++t) M = fmaxf(M, redM[tid][t]);
        float L = 0.f;
        for (int t = 0; t < 16; ++t) L += redL[tid][t] * __expf(redM[tid][t] - M);
        Mrow[tid] = M;
        Rlrow[tid] = 1.0f / L;
    }
    __syncthreads();

    float mr[4], rl[4];
    #pragma unroll
    for (int i = 0; i < 4; ++i) {
        mr[i] = Mrow[ty * 4 + i];
        rl[i] = Rlrow[ty * 4 + i];
    }
    float O[4][4] = {};

    // ---------------- pass B: p-write + PV ----------------
    for (int kt = 0; kt < 32; ++kt) {
        __syncthreads();
        for (int idx = tid; idx < 4096; idx += 256) {
            int k = idx >> 6, d = idx & 63;
            KVs[d][k] = Kh[base + (size_t)(kt * 64 + k) * DK + d];
        }
        __syncthreads();

        float s[4][4] = {};
        #pragma unroll 8
        for (int d = 0; d < 64; ++d) {
            float4 a4 = *(const float4*)&Qt[d][ty << 2];
            float4 b4 = *(const float4*)&KVs[d][tx << 2];
            float av[4] = {a4.x, a4.y, a4.z, a4.w};
            float bv[4] = {b4.x, b4.y, b4.z, b4.w};
            #pragma unroll
            for (int i = 0; i < 4; ++i)
                #pragma unroll
                for (int j = 0; j < 4; ++j)
                    s[i][j] = fmaf(av[i], bv[j], s[i][j]);
        }
        #pragma unroll
        for (int i = 0; i < 4; ++i) {
            float4 p4;
            p4.x = __expf(s[i][0] * 0.125f - mr[i]) * rl[i];
            p4.y = __expf(s[i][1] * 0.125f - mr[i]) * rl[i];
            p4.z = __expf(s[i][2] * 0.125f - mr[i]) * rl[i];
            p4.w = __expf(s[i][3] * 0.125f - mr[i]) * rl[i];
            *(float4*)&Ps[ty * 4 + i][tx << 2] = p4;
            *(float4*)&attnW[(size_t)(bh * SS + q0 + ty * 4 + i) * SS +
                             kt * 64 + (tx << 2)] = p4;
        }
        __syncthreads();
        // stage V tile natural layout [k][d]
        for (int idx = tid; idx < 1024; idx += 256) {
            int k = idx >> 4, c = idx & 15;
            *(float4*)&KVs[k][c << 2] =
                *(const float4*)&Vh[base + (size_t)(kt * 64 + k) * DK + (c << 2)];
        }
        __syncthreads();

        #pragma unroll 8
        for (int k = 0; k < 64; ++k) {
            float4 v4 = *(const float4*)&KVs[k][tx << 2];
            #pragma unroll
            for (int i = 0; i < 4; ++i) {
                float p = Ps[ty * 4 + i][k];
                O[i][0] = fmaf(p, v4.x, O[i][0]);
                O[i][1] = fmaf(p, v4.y, O[i][1]);
                O[i][2] = fmaf(p, v4.z, O[i][2]);
                O[i][3] = fmaf(p, v4.w, O[i][3]);
            }
        }
    }

    // write ctx in [B,S,768] layout (col = h*64 + d)
    const int b_ = bh / HH, h_ = bh % HH;
    #pragma unroll
    for (int i = 0; i < 4; ++i) {
        float4 o4 = {O[i][0], O[i][1], O[i][2], O[i][3]};
        *(float4*)&ctx[(size_t)(b_ * SS + q0 + ty * 4 + i) * DM +
                       h_ * DK + (tx << 2)] = o4;
    }
}

extern "C" void kernel_launch(void* const* d_in, const int* in_sizes, int n_in,
                              void* d_out, int out_size, void* d_ws, size_t ws_size,
                              hipStream_t stream) {
    const float* q   = (const float*)d_in[0];
    const float* k   = (const float*)d_in[1];
    const float* v   = (const float*)d_in[2];
    const float* w_q = (const float*)d_in[3];
    const float* b_q = (const float*)d_in[4];
    const float* w_k = (const float*)d_in[5];
    const float* b_k = (const float*)d_in[6];
    const float* w_v = (const float*)d_in[7];
    const float* b_v = (const float*)d_in[8];
    const float* w_o = (const float*)d_in[9];
    const float* b_o = (const float*)d_in[10];

    float* out   = (float*)d_out;                    // [2,2048,768]
    float* attnW = out + (size_t)2 * SS * DM;        // [2,12,2048,2048]

    float* ws  = (float*)d_ws;
    float* Qh  = ws;                                 // [B,H,S,64]
    float* Kh  = ws + (size_t)3145728;
    float* Vh  = ws + (size_t)6291456;
    float* ctx = ws + (size_t)9437184;               // [B,S,768]

    dim3 gg(12, 64), blk(256);
    gemm_bias_kernel<true><<<gg, blk, 0, stream>>>(q, w_q, b_q, Qh);
    gemm_bias_kernel<true><<<gg, blk, 0, stream>>>(k, w_k, b_k, Kh);
    gemm_bias_kernel<true><<<gg, blk, 0, stream>>>(v, w_v, b_v, Vh);

    attn_kernel<<<dim3(32, 24), blk, 0, stream>>>(Qh, Kh, Vh, attnW, ctx);

    gemm_bias_kernel<false><<<gg, blk, 0, stream>>>(ctx, w_o, b_o, out);
}